// Round 5
// baseline (1351.379 us; speedup 1.0000x reference)
//
#include <hip/hip_runtime.h>
#include <math.h>

#define DEV __device__ __forceinline__

constexpr int B_   = 2;
constexpr int C_IN = 8;
constexpr int H_   = 64;
constexpr int F_   = 257;
constexpr int T_   = 188;
constexpr int NFFT = 512;
constexpr int HOP  = 256;
constexpr int LEN  = 48000;
constexpr int PADL = 256;
constexpr int FT   = F_ * T_;
constexpr float EPSV  = 1e-4f;
constexpr float SLOPEV = 0.01f;
constexpr float PI2 = 6.283185307179586f;

typedef __attribute__((ext_vector_type(8))) short short8;
typedef __attribute__((ext_vector_type(4))) float float4v;

DEV float lrelu_f(float x) { return x > 0.f ? x : SLOPEV * x; }
DEV float snap_f(float x) {
  if (x >= 0.f && x < EPSV) return EPSV;
  if (x < 0.f && x > -EPSV) return -EPSV;
  return x;
}
DEV float modexp_f(float x) {
  const float em = 148.4131591025766f; // e^5
  return x > 5.f ? (x - 5.f) * em + em : expf(x);
}
DEV void cexp_f(float tr, float ti, float& er, float& ei) {
  float e = modexp_f(tr) - 1.f;
  float s, c;
  sincosf(ti - 1.f, &s, &c);
  er = e * c; ei = e * s;
}
DEV float sigmoid_f(float x) { return 1.f / (1.f + expf(-x)); }

DEV short f2bf(float x) {   // RNE float->bf16
  unsigned u = __float_as_uint(x);
  unsigned r = (u + 0x7fffu + ((u >> 16) & 1u)) >> 16;
  return (short)r;
}
DEV float bf2f(short h) {
  return __uint_as_float(((unsigned)(unsigned short)h) << 16);
}

// ---------------- STFT: folded rotation DFT, balanced 320-thread block ------
__global__ __launch_bounds__(320) void k_stft(const float* __restrict__ mix,
                                              float* __restrict__ out) {
  __shared__ float xw[NFFT], xu[256], xv[256];
  int blk = blockIdx.x;
  int t = blk % T_;
  int bc = blk / T_;
  int c = bc % C_IN;
  int b = bc / C_IN;
  int tid = threadIdx.x;
  for (int n = tid; n < NFFT; n += 320) {
    int g = t * HOP + n - PADL;
    if (g < 0) g = -g;
    if (g >= LEN) g = 2 * LEN - 2 - g;
    float win = 0.5f - 0.5f * cosf((PI2 / NFFT) * n);
    xw[n] = mix[(b * C_IN + c) * LEN + g] * win;
  }
  __syncthreads();
  for (int n = tid + 1; n < 256; n += 320) {
    xu[n] = xw[n] + xw[NFFT - n];
    xv[n] = xw[n] - xw[NFFT - n];
  }
  __syncthreads();
  int f = tid;
  if (f < F_) {
    float sd, cd;
    sincosf((PI2 / NFFT) * f, &sd, &cd);
    float cs = cd, sn = sd, re = 0.f, im = 0.f;
    for (int n = 1; n < 256; ++n) {
      re += xu[n] * cs;
      im -= xv[n] * sn;
      float t2 = cs * cd - sn * sd;
      sn = sn * cd + cs * sd;
      cs = t2;
    }
    re += xw[0] + xw[256] * (1.f - 2.f * (f & 1));
    out[((b * 2 + 0) * C_IN + c) * FT + f * T_ + t] = re;
    out[((b * 2 + 1) * C_IN + c) * FT + f * T_ + t] = im;
  }
}

// ---------- frequency mixing: complex (F x F) matvec per (b,c,t) ----------
template<int CH>
__global__ void k_fmix(const float* __restrict__ X, const float* __restrict__ W,
                       const float* __restrict__ bias, float* __restrict__ Y) {
  int fo = blockIdx.x;
  int bc = blockIdx.y; int c = bc % CH; int b = bc / CH;
  int t = threadIdx.x;
  if (t >= T_) return;
  const float* wr = W + fo * F_;
  const float* wi = W + F_ * F_ + fo * F_;
  const float* xr = X + ((b * 2 + 0) * CH + c) * FT + t;
  const float* xi = X + ((b * 2 + 1) * CH + c) * FT + t;
  float ar = 0.f, ai = 0.f;
  for (int fi = 0; fi < F_; ++fi) {
    float wrv = wr[fi], wiv = wi[fi];
    float xrv = xr[fi * T_], xiv = xi[fi * T_];
    ar += wrv * xrv - wiv * xiv;
    ai += wrv * xiv + wiv * xrv;
  }
  float br = bias[fo], bi = bias[F_ + fo];
  Y[((b * 2 + 0) * CH + c) * FT + fo * T_ + t] = ar + br - bi;
  Y[((b * 2 + 1) * CH + c) * FT + fo * T_ + t] = ai + br + bi;
}

// ======== repack bodies (A-fragment order, hi/lo bf16 split) ========
template<int CIN, int K>
DEV void repack_real_body(const float* __restrict__ W, short* __restrict__ wpk, int i) {
  constexpr int CC = (CIN >= 32) ? (CIN / 32) : 1;
  constexpr int NSTEP = (CIN * K + 31) / 32;
  int total = 2 * NSTEP * 4 * 64 * 8;
  if (i >= total) return;
  int j = i & 7;
  int lane = (i >> 3) & 63;
  int mt = (i >> 9) & 3;
  int s = (i >> 11) % NSTEP;
  int split = i / (NSTEP * 2048);
  int q = lane >> 4;
  int m = mt * 16 + (lane & 15);
  int tap = s / CC;
  int c = (s % CC) * 32 + q * 8 + j;
  float w = 0.f;
  if (c < CIN && tap < K) w = W[(m * CIN + c) * K + tap];
  short hi = f2bf(w);
  wpk[i] = split ? f2bf(w - bf2f(hi)) : hi;
}

// CIN2==128: staged channel cs = half*64 + hpair*2 + p  (h = half*32 + hpair)
// CIN2==16 : p-major, taps via quad
template<int CIN2, int COUT2, int K>
DEV void repack_cplx_body(const float* __restrict__ W, short* __restrict__ wpk, int i) {
  constexpr int CIN = CIN2 / 2, COUT = COUT2 / 2;
  constexpr int NSTEP = CIN2 * K / 32;
  constexpr int MT = (COUT2 + 15) / 16;
  int total = 2 * NSTEP * MT * 64 * 8;
  if (i >= total) return;
  int j = i & 7;
  int lane = (i >> 3) & 63;
  int idx = i >> 9;
  int mt = idx % MT; idx /= MT;
  int s = idx % NSTEP;
  int split = idx / NSTEP;
  int q = lane >> 4;
  int m = mt * 16 + (lane & 15);
  int tap, pi, ci;
  if constexpr (CIN2 == 128) {
    tap = 0;
    int cs = s * 32 + q * 8 + j;       // staged k index
    int half = cs / 64, r = cs % 64;
    ci = half * 32 + r / 2;
    pi = r & 1;
  } else {
    tap = s * 2 + (q >> 1);
    int cs = (q & 1) * 8 + j;
    pi = cs / CIN;
    ci = cs % CIN;
  }
  float w = 0.f;
  if (m < COUT2) {
    int po = m / COUT, ho = m % COUT;
    float wr = W[((0 * COUT + ho) * CIN + ci) * K + tap];
    float wi = W[((1 * COUT + ho) * CIN + ci) * K + tap];
    w = (po == pi) ? wr : (po == 0 ? -wi : wi);
  }
  short hi = f2bf(w);
  wpk[i] = split ? f2bf(w - bf2f(hi)) : hi;
}

__global__ __launch_bounds__(256) void k_repack_all(
    const float* c1r_w, const float* c1i_w, const float* c2r_w, const float* c2i_w,
    const float* c3r_w, const float* c3i_w, const float* c4r_w, const float* c4i_w,
    const float* c1_w, const float* c2_w, const float* c3_w, const float* c4_w,
    const float* f1_w, const float* f2_w,
    short* o0, short* o1, short* o2, short* o3, short* o4, short* o5, short* o6,
    short* o7, short* o8, short* o9, short* o10, short* o11, short* o12, short* o13) {
  int i = blockIdx.x * 256 + threadIdx.x;
  switch (blockIdx.y) {
    case 0:  repack_real_body<C_IN, 1>(c1r_w, o0, i); break;
    case 1:  repack_real_body<H_,   1>(c1i_w, o1, i); break;
    case 2:  repack_real_body<H_,   8>(c2r_w, o2, i); break;
    case 3:  repack_real_body<H_,   8>(c2i_w, o3, i); break;
    case 4:  repack_real_body<C_IN, 1>(c3r_w, o4, i); break;
    case 5:  repack_real_body<H_,   1>(c3i_w, o5, i); break;
    case 6:  repack_real_body<H_,   8>(c4r_w, o6, i); break;
    case 7:  repack_real_body<H_,   8>(c4i_w, o7, i); break;
    case 8:  repack_cplx_body<128, 128, 1>(c1_w, o8, i); break;
    case 9:  repack_cplx_body<16,  128, 8>(c2_w, o9, i); break;
    case 10: repack_cplx_body<128, 128, 1>(c3_w, o10, i); break;
    case 11: repack_cplx_body<16,  128, 8>(c4_w, o11, i); break;
    case 12: repack_cplx_body<128, 16,  1>(f1_w, o12, i); break;
    case 13: repack_cplx_body<128, 2,   1>(f2_w, o13, i); break;
  }
}

// ======== MFMA real conv with fused prologue ========
// PRO: 0 = none, 1 = lrelu on p==0 input, 2 = cLog (reads both parts)
template<int CIN, int K, int PRO>
__global__ __launch_bounds__(256) void k_conv_mfma(
    const float* __restrict__ X, const short* __restrict__ wpk,
    const float* __restrict__ bias, float* __restrict__ Y) {
  constexpr int CC = (CIN >= 32) ? (CIN / 32) : 1;
  constexpr int NSTEP = (CIN * K + 31) / 32;
  constexpr int PITCH = 72;
  constexpr int ROWS = 192 + (K - 1);
  __shared__ short xs_hi[ROWS * PITCH];
  __shared__ short xs_lo[ROWS * PITCH];
  int f = blockIdx.x;
  int bp = blockIdx.y; int p = bp & 1; int b = bp >> 1;
  int tid = threadIdx.x;

  for (int i = tid; i < ROWS * PITCH; i += 256) { xs_hi[i] = 0; xs_lo[i] = 0; }
  __syncthreads();

  const float* Xr_ = X + (size_t)((b * 2 + 0) * CIN) * FT + f * T_;
  const float* Xi_ = X + (size_t)((b * 2 + 1) * CIN) * FT + f * T_;
  const float* Xp  = X + (size_t)((b * 2 + p) * CIN) * FT + f * T_;
  for (int i = tid; i < CIN * T_; i += 256) {
    int c = i / T_, t = i % T_;
    float v;
    if (PRO == 2) {
      float re = snap_f(Xr_[c * FT + t]);
      float im = snap_f(Xi_[c * FT + t]);
      v = (p == 0) ? logf(sqrtf(im * im + re * re + EPSV * EPSV) + 1.f)
                   : atanf(im / re);
    } else {
      v = Xp[c * FT + t];
      if (PRO == 1 && p == 0) v = lrelu_f(v);
    }
    short hi = f2bf(v);
    short lo = f2bf(v - bf2f(hi));
    int r = t + (K - 1);
    xs_hi[r * PITCH + c] = hi;
    xs_lo[r * PITCH + c] = lo;
  }
  __syncthreads();

  int lane = tid & 63;
  int wv = __builtin_amdgcn_readfirstlane(tid >> 6);
  int q = lane >> 4;
  int n = lane & 15;
  int wbase = wv * 48;

  float4v acc[4][3];
  #pragma unroll
  for (int mt = 0; mt < 4; ++mt)
    #pragma unroll
    for (int nt = 0; nt < 3; ++nt) acc[mt][nt] = (float4v)(0.f);

  const short8* wp = (const short8*)wpk;
  for (int s = 0; s < NSTEP; ++s) {
    int tap = s / CC;
    int c0 = (s % CC) * 32;
    short8 Bh[3], Bl[3];
    #pragma unroll
    for (int nt = 0; nt < 3; ++nt) {
      int off = (wbase + nt * 16 + n + tap) * PITCH + c0 + q * 8;
      Bh[nt] = *(const short8*)&xs_hi[off];
      Bl[nt] = *(const short8*)&xs_lo[off];
    }
    #pragma unroll
    for (int mt = 0; mt < 4; ++mt) {
      short8 Ah = wp[((0 * NSTEP + s) * 4 + mt) * 64 + lane];
      short8 Al = wp[((1 * NSTEP + s) * 4 + mt) * 64 + lane];
      #pragma unroll
      for (int nt = 0; nt < 3; ++nt) {
        acc[mt][nt] = __builtin_amdgcn_mfma_f32_16x16x32_bf16(Ah, Bh[nt], acc[mt][nt], 0, 0, 0);
        acc[mt][nt] = __builtin_amdgcn_mfma_f32_16x16x32_bf16(Ah, Bl[nt], acc[mt][nt], 0, 0, 0);
        acc[mt][nt] = __builtin_amdgcn_mfma_f32_16x16x32_bf16(Al, Bh[nt], acc[mt][nt], 0, 0, 0);
      }
    }
  }

  float* Yp = Y + (size_t)((b * 2 + p) * H_) * FT + f * T_;
  #pragma unroll
  for (int nt = 0; nt < 3; ++nt) {
    int t = wbase + nt * 16 + n;
    if (t >= T_) continue;
    #pragma unroll
    for (int mt = 0; mt < 4; ++mt) {
      #pragma unroll
      for (int r = 0; r < 4; ++r) {
        int h = mt * 16 + q * 4 + r;
        Yp[h * FT + t] = acc[mt][nt][r] + bias[h];
      }
    }
  }
}

// ======== MFMA complex conv CIN2=128 K=1, fused prologue ========
// PRO: 1 = cexp+trelu(X0), 2 = cmul(X0,X1)+trelu. LDS halves by h: cs=(h%32)*2+p
template<int COUT2, int PRO>
__global__ __launch_bounds__(256) void k_cconv128(
    const float* __restrict__ X0, const float* __restrict__ X1,
    const short* __restrict__ wpk,
    const float* __restrict__ at, const float* __restrict__ ab,
    const float* __restrict__ bias, float* __restrict__ Y) {
  constexpr int MT = (COUT2 + 15) / 16;
  constexpr int COUT = COUT2 / 2;
  constexpr int NSTEP = 4;
  constexpr int PITCH = 72;
  __shared__ short xs_hi[192 * PITCH];
  __shared__ short xs_lo[192 * PITCH];
  __shared__ float coef[6][64];
  int f = blockIdx.x;
  int b = blockIdx.y;
  int tid = threadIdx.x;
  int lane = tid & 63;
  int wv = __builtin_amdgcn_readfirstlane(tid >> 6);
  int q = lane >> 4;
  int n = lane & 15;
  int wbase = wv * 48;

  if (tid < 64) {
    int h = tid;
    coef[0][h] = at[(0 * H_ + h) * F_ + f];
    coef[1][h] = at[(1 * H_ + h) * F_ + f];
    coef[2][h] = at[(2 * H_ + h) * F_ + f];
    coef[3][h] = at[(3 * H_ + h) * F_ + f];
    coef[4][h] = ab[h * F_ + f];
    coef[5][h] = ab[(H_ + h) * F_ + f];
  }
  for (int i = tid; i < 192 * PITCH; i += 256) { xs_hi[i] = 0; xs_lo[i] = 0; }

  const float* b0r = X0 + (size_t)((b * 2 + 0) * H_) * FT + f * T_;
  const float* b0i = X0 + (size_t)((b * 2 + 1) * H_) * FT + f * T_;
  const float* b1r = X1 + (size_t)((b * 2 + 0) * H_) * FT + f * T_;
  const float* b1i = X1 + (size_t)((b * 2 + 1) * H_) * FT + f * T_;

  float4v acc[MT][3];
  #pragma unroll
  for (int mt = 0; mt < MT; ++mt)
    #pragma unroll
    for (int nt = 0; nt < 3; ++nt) acc[mt][nt] = (float4v)(0.f);

  const short8* wp = (const short8*)wpk;
  for (int half = 0; half < 2; ++half) {
    __syncthreads();
    for (int i = tid; i < 32 * T_; i += 256) {
      int hh = i / T_, t = i % T_;
      int h = half * 32 + hh;
      float xr = b0r[h * FT + t], xi = b0i[h * FT + t];
      float vr, vi;
      if (PRO == 1) {
        float er, ei;
        cexp_f(xr, xi, er, ei);
        vr = lrelu_f(er * coef[0][h] + ei * coef[1][h] + coef[4][h]);
        vi = lrelu_f(er * coef[2][h] + ei * coef[3][h] + coef[5][h]);
      } else {
        float yr = b1r[h * FT + t], yi = b1i[h * FT + t];
        float mr = xr * yr - xi * yi;
        float mi = xr * yi + xi * yr;
        vr = lrelu_f(mr * coef[0][h] + mi * coef[1][h] + coef[4][h]);
        vi = lrelu_f(mr * coef[2][h] + mi * coef[3][h] + coef[5][h]);
      }
      int cs0 = hh * 2, cs1 = hh * 2 + 1;
      short hr = f2bf(vr), hi2 = f2bf(vi);
      xs_hi[t * PITCH + cs0] = hr;
      xs_lo[t * PITCH + cs0] = f2bf(vr - bf2f(hr));
      xs_hi[t * PITCH + cs1] = hi2;
      xs_lo[t * PITCH + cs1] = f2bf(vi - bf2f(hi2));
    }
    __syncthreads();
    #pragma unroll
    for (int s2 = 0; s2 < 2; ++s2) {
      int s = half * 2 + s2;
      short8 Bh[3], Bl[3];
      #pragma unroll
      for (int nt = 0; nt < 3; ++nt) {
        int off = (wbase + nt * 16 + n) * PITCH + s2 * 32 + q * 8;
        Bh[nt] = *(const short8*)&xs_hi[off];
        Bl[nt] = *(const short8*)&xs_lo[off];
      }
      #pragma unroll
      for (int mt = 0; mt < MT; ++mt) {
        short8 Ah = wp[((0 * NSTEP + s) * MT + mt) * 64 + lane];
        short8 Al = wp[((1 * NSTEP + s) * MT + mt) * 64 + lane];
        #pragma unroll
        for (int nt = 0; nt < 3; ++nt) {
          acc[mt][nt] = __builtin_amdgcn_mfma_f32_16x16x32_bf16(Ah, Bh[nt], acc[mt][nt], 0, 0, 0);
          acc[mt][nt] = __builtin_amdgcn_mfma_f32_16x16x32_bf16(Ah, Bl[nt], acc[mt][nt], 0, 0, 0);
          acc[mt][nt] = __builtin_amdgcn_mfma_f32_16x16x32_bf16(Al, Bh[nt], acc[mt][nt], 0, 0, 0);
        }
      }
    }
  }

  float* Yp = Y + (size_t)b * COUT2 * FT + f * T_;
  #pragma unroll
  for (int nt = 0; nt < 3; ++nt) {
    int t = wbase + nt * 16 + n;
    if (t >= T_) continue;
    #pragma unroll
    for (int mt = 0; mt < MT; ++mt) {
      #pragma unroll
      for (int r = 0; r < 4; ++r) {
        int o2 = mt * 16 + q * 4 + r;
        if (o2 >= COUT2) continue;
        int po = o2 / COUT, ho = o2 % COUT;
        float br = bias[ho], bi = bias[COUT + ho];
        float badd = (po == 0) ? br - bi : br + bi;
        Yp[o2 * FT + t] = acc[mt][nt][r] + badd;
      }
    }
  }
}

// ======== MFMA complex conv, CIN2=16, K=8 (real-ified) ========
__global__ __launch_bounds__(256) void k_cconv16(
    const float* __restrict__ X, const short* __restrict__ wpk,
    const float* __restrict__ bias, float* __restrict__ Y) {
  constexpr int MT = 8, NSTEP = 4, PITCH = 24, ROWS = 199, COUT = 64, COUT2 = 128;
  __shared__ short xs_hi[ROWS * PITCH];
  __shared__ short xs_lo[ROWS * PITCH];
  int f = blockIdx.x;
  int b = blockIdx.y;
  int tid = threadIdx.x;

  for (int i = tid; i < ROWS * PITCH; i += 256) { xs_hi[i] = 0; xs_lo[i] = 0; }
  __syncthreads();

  const float* Xp = X + (size_t)b * 16 * FT + f * T_;
  for (int i = tid; i < 16 * T_; i += 256) {
    int c = i / T_, t = i % T_;
    float v = Xp[c * FT + t];
    short hi = f2bf(v);
    short lo = f2bf(v - bf2f(hi));
    xs_hi[(t + 7) * PITCH + c] = hi;
    xs_lo[(t + 7) * PITCH + c] = lo;
  }
  __syncthreads();

  int lane = tid & 63;
  int wv = __builtin_amdgcn_readfirstlane(tid >> 6);
  int q = lane >> 4;
  int n = lane & 15;
  int wbase = wv * 48;

  float4v acc[MT][3];
  #pragma unroll
  for (int mt = 0; mt < MT; ++mt)
    #pragma unroll
    for (int nt = 0; nt < 3; ++nt) acc[mt][nt] = (float4v)(0.f);

  const short8* wp = (const short8*)wpk;
  #pragma unroll
  for (int s = 0; s < NSTEP; ++s) {
    int tap = s * 2 + (q >> 1);
    int coff = (q & 1) * 8;
    short8 Bh[3], Bl[3];
    #pragma unroll
    for (int nt = 0; nt < 3; ++nt) {
      int off = (wbase + nt * 16 + n + tap) * PITCH + coff;
      Bh[nt] = *(const short8*)&xs_hi[off];
      Bl[nt] = *(const short8*)&xs_lo[off];
    }
    #pragma unroll
    for (int mt = 0; mt < MT; ++mt) {
      short8 Ah = wp[((0 * NSTEP + s) * MT + mt) * 64 + lane];
      short8 Al = wp[((1 * NSTEP + s) * MT + mt) * 64 + lane];
      #pragma unroll
      for (int nt = 0; nt < 3; ++nt) {
        acc[mt][nt] = __builtin_amdgcn_mfma_f32_16x16x32_bf16(Ah, Bh[nt], acc[mt][nt], 0, 0, 0);
        acc[mt][nt] = __builtin_amdgcn_mfma_f32_16x16x32_bf16(Ah, Bl[nt], acc[mt][nt], 0, 0, 0);
        acc[mt][nt] = __builtin_amdgcn_mfma_f32_16x16x32_bf16(Al, Bh[nt], acc[mt][nt], 0, 0, 0);
      }
    }
  }

  float* Yp = Y + (size_t)b * COUT2 * FT + f * T_;
  #pragma unroll
  for (int nt = 0; nt < 3; ++nt) {
    int t = wbase + nt * 16 + n;
    if (t >= T_) continue;
    #pragma unroll
    for (int mt = 0; mt < MT; ++mt) {
      #pragma unroll
      for (int r = 0; r < 4; ++r) {
        int o2 = mt * 16 + q * 4 + r;
        int po = o2 / COUT, ho = o2 % COUT;
        float br = bias[ho], bi = bias[COUT + ho];
        float badd = (po == 0) ? br - bi : br + bi;
        Yp[o2 * FT + t] = acc[mt][nt][r] + badd;
      }
    }
  }
}

// ---------------- cExp (out-of-place; output also feeds k_fuse) -----------
__global__ void k_cexp(const float* __restrict__ X, float* __restrict__ Y) {
  int i = blockIdx.x * blockDim.x + threadIdx.x;
  if (i >= B_ * H_ * FT) return;
  int b = i / (H_ * FT);
  int r = i % (H_ * FT);
  int i0 = (b * 2) * H_ * FT + r;
  int i1 = i0 + H_ * FT;
  float er, ei;
  cexp_f(X[i0], X[i1], er, ei);
  Y[i0] = er;
  Y[i1] = ei;
}

__global__ void k_td1(const float* __restrict__ ts, const float* __restrict__ t8,
                      float* __restrict__ td1) {
  int i = blockIdx.x * blockDim.x + threadIdx.x;
  if (i >= B_ * 2 * FT) return;
  int bp = i / FT; int r = i % FT;
  const float* a = ts + bp * C_IN * FT + r;
  const float* c2 = t8 + bp * C_IN * FT + r;
  float acc = 0.f;
  #pragma unroll
  for (int c = 0; c < C_IN; ++c) acc += a[c * FT] - c2[c * FT];
  td1[i] = acc * (1.f / C_IN);
}

// ------------- fuse: cconv(concat) -> tgate -> blend -------------
__global__ void k_fuse(const float* __restrict__ tl1, const float* __restrict__ tl2,
                       const float* __restrict__ td1, const float* __restrict__ td2,
                       const float* __restrict__ cw, const float* __restrict__ cwb,
                       const float* __restrict__ fgt, const float* __restrict__ fgb,
                       float* __restrict__ td) {
  int i = blockIdx.x * blockDim.x + threadIdx.x;
  if (i >= B_ * FT) return;
  int b = i / FT; int r = i % FT; int f = r / T_;
  const float* x1r = tl1 + (b * 2) * H_ * FT + r;
  const float* x1i = x1r + H_ * FT;
  const float* x2r = tl2 + (b * 2) * H_ * FT + r;
  const float* x2i = x2r + H_ * FT;
  float fr = 0.f, fi = 0.f;
  for (int c = 0; c < H_; ++c) {
    float w1r = cw[c], w2r = cw[H_ + c], w1i = cw[2 * H_ + c], w2i = cw[3 * H_ + c];
    float a1r = x1r[c * FT], a1i = x1i[c * FT];
    float a2r = x2r[c * FT], a2i = x2i[c * FT];
    fr += w1r * a1r - w1i * a1i + w2r * a2r - w2i * a2i;
    fi += w1r * a1i + w1i * a1r + w2r * a2i + w2i * a2r;
  }
  fr += cwb[0] - cwb[1];
  fi += cwb[0] + cwb[1];
  float t00 = fgt[f], t01 = fgt[F_ + f], t10 = fgt[2 * F_ + f], t11 = fgt[3 * F_ + f];
  float gr = sigmoid_f(fr * t00 + fi * t01 + fgb[f]);
  float gi = sigmoid_f(fr * t10 + fi * t11 + fgb[F_ + f]);
  float gg = gr * gi + (1.f - gr) * (1.f - gi);
  int i0 = (b * 2) * FT + r, i1 = i0 + FT;
  td[i0] = td1[i0] * gg + td2[i0] * (1.f - gg);
  td[i1] = td1[i1] * gg + td2[i1] * (1.f - gg);
}

// ------------- iSTFT frames: folded rotation inverse DFT -------------
__global__ __launch_bounds__(320) void k_iframes(const float* __restrict__ sp,
                                                 float* __restrict__ frames) {
  __shared__ float Xr[F_], Xi[F_];
  int blk = blockIdx.x;
  int t = blk % T_;
  int b = blk / T_;
  int tid = threadIdx.x;
  for (int i = tid; i < F_; i += 320) {
    Xr[i] = sp[(b * 2 + 0) * FT + i * T_ + t];
    Xi[i] = sp[(b * 2 + 1) * FT + i * T_ + t];
  }
  __syncthreads();
  int n = tid;
  if (n <= 256) {
    float sd, cd;
    sincosf((PI2 / NFFT) * n, &sd, &cd);
    float cs = cd, sn = sd;
    float ac = 0.f, as = 0.f;
    for (int f = 1; f < 256; ++f) {
      ac += Xr[f] * cs;
      as += Xi[f] * sn;
      float t2 = cs * cd - sn * sd;
      sn = sn * cd + cs * sd;
      cs = t2;
    }
    float base = Xr[0] + Xr[256] * (1.f - 2.f * (n & 1));
    float win = 0.5f - 0.5f * cd;          // hann symmetric: win(n)==win(512-n)
    float scale = win * (1.f / NFFT);
    float* fr = frames + (size_t)(b * T_ + t) * NFFT;
    fr[n] = (base + 2.f * ac - 2.f * as) * scale;
    if (n >= 1 && n <= 255)
      fr[NFFT - n] = (base + 2.f * ac + 2.f * as) * scale;
  }
}

// ------------- overlap-add + wsum normalize + center-crop -------------
__global__ void k_ola(const float* __restrict__ frames, float* __restrict__ out) {
  int i = blockIdx.x * blockDim.x + threadIdx.x;
  if (i >= B_ * LEN) return;
  int b = i / LEN; int j = i % LEN;
  int p = j + PADL;
  int t0 = p / HOP; int n0 = p - t0 * HOP;
  float acc = 0.f, wsum = 0.f;
  if (t0 < T_) {
    acc += frames[(b * T_ + t0) * NFFT + n0];
    float w = 0.5f - 0.5f * cosf((PI2 / NFFT) * n0);
    wsum += w * w;
  }
  int t1 = t0 - 1, n1 = n0 + HOP;
  if (t1 >= 0 && t1 < T_) {
    acc += frames[(b * T_ + t1) * NFFT + n1];
    float w = 0.5f - 0.5f * cosf((PI2 / NFFT) * n1);
    wsum += w * w;
  }
  out[i] = acc / fmaxf(wsum, 1e-11f);
}

extern "C" void kernel_launch(void* const* d_in, const int* in_sizes, int n_in,
                              void* d_out, int out_size, void* d_ws, size_t ws_size,
                              hipStream_t stream) {
  const float* mix   = (const float*)d_in[0];
  const float* fs_w  = (const float*)d_in[1];
  const float* fs_b  = (const float*)d_in[2];
  const float* fr_w  = (const float*)d_in[3];
  const float* fr_b  = (const float*)d_in[4];
  const float* c1r_w = (const float*)d_in[5];
  const float* c1r_b = (const float*)d_in[6];
  const float* c1i_w = (const float*)d_in[7];
  const float* c1i_b = (const float*)d_in[8];
  const float* c1_w  = (const float*)d_in[9];
  const float* c1_b  = (const float*)d_in[10];
  const float* c2r_w = (const float*)d_in[11];
  const float* c2r_b = (const float*)d_in[12];
  const float* c2i_w = (const float*)d_in[13];
  const float* c2i_b = (const float*)d_in[14];
  const float* c2_w  = (const float*)d_in[15];
  const float* c2_b  = (const float*)d_in[16];
  const float* a1_t  = (const float*)d_in[17];
  const float* a1_b  = (const float*)d_in[18];
  const float* a2_t  = (const float*)d_in[19];
  const float* a2_b  = (const float*)d_in[20];
  const float* c3r_w = (const float*)d_in[21];
  const float* c3r_b = (const float*)d_in[22];
  const float* c3i_w = (const float*)d_in[23];
  const float* c3i_b = (const float*)d_in[24];
  const float* c3_w  = (const float*)d_in[25];
  const float* c3_b  = (const float*)d_in[26];
  const float* c4r_w = (const float*)d_in[27];
  const float* c4r_b = (const float*)d_in[28];
  const float* c4i_w = (const float*)d_in[29];
  const float* c4i_b = (const float*)d_in[30];
  const float* c4_w  = (const float*)d_in[31];
  const float* c4_b  = (const float*)d_in[32];
  const float* a3_t  = (const float*)d_in[33];
  const float* a3_b  = (const float*)d_in[34];
  const float* a4_t  = (const float*)d_in[35];
  const float* a4_b  = (const float*)d_in[36];
  const float* f1_w  = (const float*)d_in[37];
  const float* f1_b  = (const float*)d_in[38];
  const float* f2_w  = (const float*)d_in[39];
  const float* f2_b  = (const float*)d_in[40];
  const float* cw_w  = (const float*)d_in[41];
  const float* cw_b  = (const float*)d_in[42];
  const float* fg_t  = (const float*)d_in[43];
  const float* fg_b  = (const float*)d_in[44];

  const size_t S8 = (size_t)B_ * 2 * C_IN * FT;
  const size_t SH = (size_t)B_ * 2 * H_ * FT;
  const size_t S1 = (size_t)B_ * 2 * FT;
  float* ws  = (float*)d_ws;
  float* ts0 = ws;
  float* ts  = ts0 + S8;
  float* A   = ts + S8;
  float* Bb  = A + SH;
  float* Cc  = Bb + SH;
  float* td1 = Cc + SH;
  float* td2 = td1 + S1;
  float* tdf = td2 + S1;
  float* tdr = tdf + S1;
  float* s8  = ts0;
  float* frames = ts0;

  short* wtail = (short*)(tdr + S1);
  constexpr int SZ_C8K1   = 2 * 1  * 4 * 64 * 8;
  constexpr int SZ_C64K1  = 2 * 2  * 4 * 64 * 8;
  constexpr int SZ_C64K8  = 2 * 16 * 4 * 64 * 8;
  constexpr int SZ_CC128  = 2 * 4  * 8 * 64 * 8;
  constexpr int SZ_CF     = 2 * 4  * 1 * 64 * 8;
  short* w_c1r = wtail;
  short* w_c1i = w_c1r + SZ_C8K1;
  short* w_c2r = w_c1i + SZ_C64K1;
  short* w_c2i = w_c2r + SZ_C64K8;
  short* w_c3r = w_c2i + SZ_C64K8;
  short* w_c3i = w_c3r + SZ_C8K1;
  short* w_c4r = w_c3i + SZ_C64K1;
  short* w_c4i = w_c4r + SZ_C64K8;
  short* w_cc1 = w_c4i + SZ_C64K8;
  short* w_cc2 = w_cc1 + SZ_CC128;
  short* w_cc3 = w_cc2 + SZ_CC128;
  short* w_cc4 = w_cc3 + SZ_CC128;
  short* w_cf1 = w_cc4 + SZ_CC128;
  short* w_cf2 = w_cf1 + SZ_CF;

  const int nH = B_ * H_ * FT;
  const int nP = B_ * FT;
  const dim3 rgrid(F_, B_ * 2);
  const dim3 cgrid(F_, B_);

  k_repack_all<<<dim3(256, 14), 256, 0, stream>>>(
      c1r_w, c1i_w, c2r_w, c2i_w, c3r_w, c3i_w, c4r_w, c4i_w,
      c1_w, c2_w, c3_w, c4_w, f1_w, f2_w,
      w_c1r, w_c1i, w_c2r, w_c2i, w_c3r, w_c3i, w_c4r, w_c4i,
      w_cc1, w_cc2, w_cc3, w_cc4, w_cf1, w_cf2);

  // STFT + frequency mixing
  k_stft<<<B_ * C_IN * T_, 320, 0, stream>>>(mix, ts0);
  k_fmix<C_IN><<<dim3(F_, B_ * C_IN), 192, 0, stream>>>(ts0, fs_w, fs_b, ts);

  // ---- branch 1 ----
  k_conv_mfma<C_IN, 1, 2><<<rgrid, 256, 0, stream>>>(ts, w_c1r, c1r_b, A);     // cLog+c1r
  k_conv_mfma<H_, 1, 1><<<rgrid, 256, 0, stream>>>(A, w_c1i, c1i_b, Bb);       // lrelu+c1i
  k_cconv128<128, 1><<<cgrid, 256, 0, stream>>>(Bb, Bb, w_cc1, a1_t, a1_b, c1_b, A); // cexp+trelu+c1
  k_conv_mfma<H_, 8, 2><<<rgrid, 256, 0, stream>>>(A, w_c2r, c2r_b, Bb);       // cLog+c2r
  k_conv_mfma<H_, 8, 1><<<rgrid, 256, 0, stream>>>(Bb, w_c2i, c2i_b, A);       // lrelu+c2i
  k_cexp<<<(nH + 255) / 256, 256, 0, stream>>>(A, Bb);                          // Bb = tl1
  k_cconv16<<<cgrid, 256, 0, stream>>>(ts, w_cc2, c2_b, A);                     // tc
  k_cconv128<16, 2><<<cgrid, 256, 0, stream>>>(Bb, A, w_cf1, a2_t, a2_b, f1_b, s8); // cmul+trelu+f1
  k_td1<<<(B_ * 2 * FT + 255) / 256, 256, 0, stream>>>(ts, s8, td1);

  // ---- branch 2 ----
  k_conv_mfma<C_IN, 1, 2><<<rgrid, 256, 0, stream>>>(ts, w_c3r, c3r_b, A);
  k_conv_mfma<H_, 1, 1><<<rgrid, 256, 0, stream>>>(A, w_c3i, c3i_b, Cc);
  k_cconv128<128, 1><<<cgrid, 256, 0, stream>>>(Cc, Cc, w_cc3, a3_t, a3_b, c3_b, A);
  k_conv_mfma<H_, 8, 2><<<rgrid, 256, 0, stream>>>(A, w_c4r, c4r_b, Cc);
  k_conv_mfma<H_, 8, 1><<<rgrid, 256, 0, stream>>>(Cc, w_c4i, c4i_b, A);
  k_cexp<<<(nH + 255) / 256, 256, 0, stream>>>(A, Cc);                          // Cc = tl2
  k_cconv16<<<cgrid, 256, 0, stream>>>(ts, w_cc4, c4_b, A);
  k_cconv128<2, 2><<<cgrid, 256, 0, stream>>>(Cc, A, w_cf2, a4_t, a4_b, f2_b, td2);

  // ---- fuse + unmix + iSTFT ----
  k_fuse<<<(nP + 255) / 256, 256, 0, stream>>>(Bb, Cc, td1, td2, cw_w, cw_b, fg_t, fg_b, tdf);
  k_fmix<1><<<dim3(F_, B_), 192, 0, stream>>>(tdf, fr_w, fr_b, tdr);
  k_iframes<<<B_ * T_, 320, 0, stream>>>(tdr, frames);
  k_ola<<<(B_ * LEN + 255) / 256, 256, 0, stream>>>(frames, (float*)d_out);
}

// Round 6
// 942.536 us; speedup vs baseline: 1.4338x; 1.4338x over previous
//
#include <hip/hip_runtime.h>
#include <math.h>

#define DEV __device__ __forceinline__

constexpr int B_   = 2;
constexpr int C_IN = 8;
constexpr int H_   = 64;
constexpr int F_   = 257;
constexpr int T_   = 188;
constexpr int TW   = 96;    // t-columns per block (T split in 2)
constexpr int NFFT = 512;
constexpr int HOP  = 256;
constexpr int LEN  = 48000;
constexpr int PADL = 256;
constexpr int FT   = F_ * T_;
constexpr float EPSV  = 1e-4f;
constexpr float SLOPEV = 0.01f;
constexpr float PI2 = 6.283185307179586f;

typedef __attribute__((ext_vector_type(8))) short short8;
typedef __attribute__((ext_vector_type(4))) float float4v;

DEV float lrelu_f(float x) { return x > 0.f ? x : SLOPEV * x; }
DEV float snap_f(float x) {
  if (x >= 0.f && x < EPSV) return EPSV;
  if (x < 0.f && x > -EPSV) return -EPSV;
  return x;
}
DEV float modexp_f(float x) {
  const float em = 148.4131591025766f; // e^5
  return x > 5.f ? (x - 5.f) * em + em : expf(x);
}
DEV void cexp_f(float tr, float ti, float& er, float& ei) {
  float e = modexp_f(tr) - 1.f;
  float s, c;
  sincosf(ti - 1.f, &s, &c);
  er = e * c; ei = e * s;
}
DEV float sigmoid_f(float x) { return 1.f / (1.f + expf(-x)); }

DEV short f2bf(float x) {   // RNE float->bf16
  unsigned u = __float_as_uint(x);
  unsigned r = (u + 0x7fffu + ((u >> 16) & 1u)) >> 16;
  return (short)r;
}
DEV float bf2f(short h) {
  return __uint_as_float(((unsigned)(unsigned short)h) << 16);
}

// ---------------- STFT: folded rotation DFT, balanced 320-thread block ------
__global__ __launch_bounds__(320) void k_stft(const float* __restrict__ mix,
                                              float* __restrict__ out) {
  __shared__ float xw[NFFT], xu[256], xv[256];
  int blk = blockIdx.x;
  int t = blk % T_;
  int bc = blk / T_;
  int c = bc % C_IN;
  int b = bc / C_IN;
  int tid = threadIdx.x;
  for (int n = tid; n < NFFT; n += 320) {
    int g = t * HOP + n - PADL;
    if (g < 0) g = -g;
    if (g >= LEN) g = 2 * LEN - 2 - g;
    float win = 0.5f - 0.5f * cosf((PI2 / NFFT) * n);
    xw[n] = mix[(b * C_IN + c) * LEN + g] * win;
  }
  __syncthreads();
  for (int n = tid + 1; n < 256; n += 320) {
    xu[n] = xw[n] + xw[NFFT - n];
    xv[n] = xw[n] - xw[NFFT - n];
  }
  __syncthreads();
  int f = tid;
  if (f < F_) {
    float sd, cd;
    sincosf((PI2 / NFFT) * f, &sd, &cd);
    float cs = cd, sn = sd, re = 0.f, im = 0.f;
    for (int n = 1; n < 256; ++n) {
      re += xu[n] * cs;
      im -= xv[n] * sn;
      float t2 = cs * cd - sn * sd;
      sn = sn * cd + cs * sd;
      cs = t2;
    }
    re += xw[0] + xw[256] * (1.f - 2.f * (f & 1));
    out[((b * 2 + 0) * C_IN + c) * FT + f * T_ + t] = re;
    out[((b * 2 + 1) * C_IN + c) * FT + f * T_ + t] = im;
  }
}

// ---------- frequency mixing: complex (F x F) matvec per (b,c,t) ----------
template<int CH>
__global__ void k_fmix(const float* __restrict__ X, const float* __restrict__ W,
                       const float* __restrict__ bias, float* __restrict__ Y) {
  int fo = blockIdx.x;
  int bc = blockIdx.y; int c = bc % CH; int b = bc / CH;
  int t = threadIdx.x;
  if (t >= T_) return;
  const float* wr = W + fo * F_;
  const float* wi = W + F_ * F_ + fo * F_;
  const float* xr = X + ((b * 2 + 0) * CH + c) * FT + t;
  const float* xi = X + ((b * 2 + 1) * CH + c) * FT + t;
  float ar = 0.f, ai = 0.f;
  for (int fi = 0; fi < F_; ++fi) {
    float wrv = wr[fi], wiv = wi[fi];
    float xrv = xr[fi * T_], xiv = xi[fi * T_];
    ar += wrv * xrv - wiv * xiv;
    ai += wrv * xiv + wiv * xrv;
  }
  float br = bias[fo], bi = bias[F_ + fo];
  Y[((b * 2 + 0) * CH + c) * FT + fo * T_ + t] = ar + br - bi;
  Y[((b * 2 + 1) * CH + c) * FT + fo * T_ + t] = ai + br + bi;
}

// ======== repack bodies (A-fragment order, hi/lo bf16 split) ========
template<int CIN, int K>
DEV void repack_real_body(const float* __restrict__ W, short* __restrict__ wpk, int i) {
  constexpr int CC = (CIN >= 32) ? (CIN / 32) : 1;
  constexpr int NSTEP = (CIN * K + 31) / 32;
  int total = 2 * NSTEP * 4 * 64 * 8;
  if (i >= total) return;
  int j = i & 7;
  int lane = (i >> 3) & 63;
  int mt = (i >> 9) & 3;
  int s = (i >> 11) % NSTEP;
  int split = i / (NSTEP * 2048);
  int q = lane >> 4;
  int m = mt * 16 + (lane & 15);
  int tap = s / CC;
  int c = (s % CC) * 32 + q * 8 + j;
  float w = 0.f;
  if (c < CIN && tap < K) w = W[(m * CIN + c) * K + tap];
  short hi = f2bf(w);
  wpk[i] = split ? f2bf(w - bf2f(hi)) : hi;
}

template<int CIN2, int COUT2, int K>
DEV void repack_cplx_body(const float* __restrict__ W, short* __restrict__ wpk, int i) {
  constexpr int CIN = CIN2 / 2, COUT = COUT2 / 2;
  constexpr int NSTEP = CIN2 * K / 32;
  constexpr int MT = (COUT2 + 15) / 16;
  int total = 2 * NSTEP * MT * 64 * 8;
  if (i >= total) return;
  int j = i & 7;
  int lane = (i >> 3) & 63;
  int idx = i >> 9;
  int mt = idx % MT; idx /= MT;
  int s = idx % NSTEP;
  int split = idx / NSTEP;
  int q = lane >> 4;
  int m = mt * 16 + (lane & 15);
  int tap, pi, ci;
  if constexpr (CIN2 == 128) {
    tap = 0;
    int cs = s * 32 + q * 8 + j;       // staged k index
    int half = cs / 64, r = cs % 64;
    ci = half * 32 + r / 2;
    pi = r & 1;
  } else {
    tap = s * 2 + (q >> 1);
    int cs = (q & 1) * 8 + j;
    pi = cs / CIN;
    ci = cs % CIN;
  }
  float w = 0.f;
  if (m < COUT2) {
    int po = m / COUT, ho = m % COUT;
    float wr = W[((0 * COUT + ho) * CIN + ci) * K + tap];
    float wi = W[((1 * COUT + ho) * CIN + ci) * K + tap];
    w = (po == pi) ? wr : (po == 0 ? -wi : wi);
  }
  short hi = f2bf(w);
  wpk[i] = split ? f2bf(w - bf2f(hi)) : hi;
}

__global__ __launch_bounds__(256) void k_repack_all(
    const float* c1r_w, const float* c1i_w, const float* c2r_w, const float* c2i_w,
    const float* c3r_w, const float* c3i_w, const float* c4r_w, const float* c4i_w,
    const float* c1_w, const float* c2_w, const float* c3_w, const float* c4_w,
    const float* f1_w, const float* f2_w,
    short* o0, short* o1, short* o2, short* o3, short* o4, short* o5, short* o6,
    short* o7, short* o8, short* o9, short* o10, short* o11, short* o12, short* o13) {
  int i = blockIdx.x * 256 + threadIdx.x;
  switch (blockIdx.y) {
    case 0:  repack_real_body<C_IN, 1>(c1r_w, o0, i); break;
    case 1:  repack_real_body<H_,   1>(c1i_w, o1, i); break;
    case 2:  repack_real_body<H_,   8>(c2r_w, o2, i); break;
    case 3:  repack_real_body<H_,   8>(c2i_w, o3, i); break;
    case 4:  repack_real_body<C_IN, 1>(c3r_w, o4, i); break;
    case 5:  repack_real_body<H_,   1>(c3i_w, o5, i); break;
    case 6:  repack_real_body<H_,   8>(c4r_w, o6, i); break;
    case 7:  repack_real_body<H_,   8>(c4i_w, o7, i); break;
    case 8:  repack_cplx_body<128, 128, 1>(c1_w, o8, i); break;
    case 9:  repack_cplx_body<16,  128, 8>(c2_w, o9, i); break;
    case 10: repack_cplx_body<128, 128, 1>(c3_w, o10, i); break;
    case 11: repack_cplx_body<16,  128, 8>(c4_w, o11, i); break;
    case 12: repack_cplx_body<128, 16,  1>(f1_w, o12, i); break;
    case 13: repack_cplx_body<128, 2,   1>(f2_w, o13, i); break;
  }
}

// ======== MFMA real conv, T-split: block=(f, b*2+p, thalf); wave=(mt-half, t-chunk)
// PRO: 0 = none, 1 = lrelu on p==0 input, 2 = cLog (reads both parts)
template<int CIN, int K, int PRO>
__global__ __launch_bounds__(256) void k_conv_mfma(
    const float* __restrict__ X, const short* __restrict__ wpk,
    const float* __restrict__ bias, float* __restrict__ Y) {
  constexpr int CC = (CIN >= 32) ? (CIN / 32) : 1;
  constexpr int NSTEP = (CIN * K + 31) / 32;
  constexpr int PITCH = 72;
  constexpr int ROWS = TW + (K - 1);
  __shared__ short xs_hi[ROWS * PITCH];
  __shared__ short xs_lo[ROWS * PITCH];
  int f = blockIdx.x;
  int bp = blockIdx.y; int p = bp & 1; int b = bp >> 1;
  int t0 = blockIdx.z * TW;
  int tid = threadIdx.x;

  for (int i = tid; i < ROWS * PITCH; i += 256) { xs_hi[i] = 0; xs_lo[i] = 0; }
  __syncthreads();

  const float* Xr_ = X + (size_t)((b * 2 + 0) * CIN) * FT + f * T_;
  const float* Xi_ = X + (size_t)((b * 2 + 1) * CIN) * FT + f * T_;
  const float* Xp  = X + (size_t)((b * 2 + p) * CIN) * FT + f * T_;
  for (int i = tid; i < CIN * ROWS; i += 256) {
    int c = i / ROWS, rr = i % ROWS;
    int t = t0 + rr - (K - 1);
    if (t < 0 || t >= T_) continue;
    float v;
    if (PRO == 2) {
      float re = snap_f(Xr_[c * FT + t]);
      float im = snap_f(Xi_[c * FT + t]);
      v = (p == 0) ? logf(sqrtf(im * im + re * re + EPSV * EPSV) + 1.f)
                   : atanf(im / re);
    } else {
      v = Xp[c * FT + t];
      if (PRO == 1 && p == 0) v = lrelu_f(v);
    }
    short hi = f2bf(v);
    short lo = f2bf(v - bf2f(hi));
    xs_hi[rr * PITCH + c] = hi;
    xs_lo[rr * PITCH + c] = lo;
  }
  __syncthreads();

  int lane = tid & 63;
  int wv = __builtin_amdgcn_readfirstlane(tid >> 6);
  int mh = wv >> 1;           // mt-half: mt in {mh*2, mh*2+1}
  int tc = wv & 1;            // t-chunk within block
  int q = lane >> 4;
  int n = lane & 15;
  int wbase = tc * 48;

  float4v acc[2][3];
  #pragma unroll
  for (int mt = 0; mt < 2; ++mt)
    #pragma unroll
    for (int nt = 0; nt < 3; ++nt) acc[mt][nt] = (float4v)(0.f);

  const short8* wp = (const short8*)wpk;
  for (int s = 0; s < NSTEP; ++s) {
    int tap = s / CC;
    int c0 = (s % CC) * 32;
    short8 Bh[3], Bl[3];
    #pragma unroll
    for (int nt = 0; nt < 3; ++nt) {
      int off = (wbase + nt * 16 + n + tap) * PITCH + c0 + q * 8;
      Bh[nt] = *(const short8*)&xs_hi[off];
      Bl[nt] = *(const short8*)&xs_lo[off];
    }
    #pragma unroll
    for (int mt = 0; mt < 2; ++mt) {
      int mtg = mh * 2 + mt;
      short8 Ah = wp[((0 * NSTEP + s) * 4 + mtg) * 64 + lane];
      short8 Al = wp[((1 * NSTEP + s) * 4 + mtg) * 64 + lane];
      #pragma unroll
      for (int nt = 0; nt < 3; ++nt) {
        acc[mt][nt] = __builtin_amdgcn_mfma_f32_16x16x32_bf16(Ah, Bh[nt], acc[mt][nt], 0, 0, 0);
        acc[mt][nt] = __builtin_amdgcn_mfma_f32_16x16x32_bf16(Ah, Bl[nt], acc[mt][nt], 0, 0, 0);
        acc[mt][nt] = __builtin_amdgcn_mfma_f32_16x16x32_bf16(Al, Bh[nt], acc[mt][nt], 0, 0, 0);
      }
    }
  }

  float* Yp = Y + (size_t)((b * 2 + p) * H_) * FT + f * T_;
  #pragma unroll
  for (int nt = 0; nt < 3; ++nt) {
    int t = t0 + wbase + nt * 16 + n;
    if (t >= T_) continue;
    #pragma unroll
    for (int mt = 0; mt < 2; ++mt) {
      #pragma unroll
      for (int r = 0; r < 4; ++r) {
        int h = (mh * 2 + mt) * 16 + q * 4 + r;
        Yp[h * FT + t] = acc[mt][nt][r] + bias[h];
      }
    }
  }
}

// ======== MFMA complex conv CIN2=128 K=1, T-split, fused prologue ========
// PRO: 1 = cexp+trelu(X0), 2 = cmul(X0,X1)+trelu. LDS channel key cs=(h%32)*2+p
template<int COUT2, int PRO>
__global__ __launch_bounds__(256) void k_cconv128(
    const float* __restrict__ X0, const float* __restrict__ X1,
    const short* __restrict__ wpk,
    const float* __restrict__ at, const float* __restrict__ ab,
    const float* __restrict__ bias, float* __restrict__ Y) {
  constexpr int MT = (COUT2 + 15) / 16;
  constexpr int MTW = (MT > 4) ? 4 : MT;
  constexpr int COUT = COUT2 / 2;
  constexpr int NSTEP = 4;
  constexpr int PITCH = 72;
  __shared__ short xs_hi[TW * PITCH];
  __shared__ short xs_lo[TW * PITCH];
  __shared__ float coef[6][64];
  int f = blockIdx.x;
  int b = blockIdx.y;
  int t0 = blockIdx.z * TW;
  int tid = threadIdx.x;
  int lane = tid & 63;
  int wv = __builtin_amdgcn_readfirstlane(tid >> 6);
  int mh = wv >> 1;
  int tc = wv & 1;
  int q = lane >> 4;
  int n = lane & 15;
  int wbase = tc * 48;

  if (tid < 64) {
    int h = tid;
    coef[0][h] = at[(0 * H_ + h) * F_ + f];
    coef[1][h] = at[(1 * H_ + h) * F_ + f];
    coef[2][h] = at[(2 * H_ + h) * F_ + f];
    coef[3][h] = at[(3 * H_ + h) * F_ + f];
    coef[4][h] = ab[h * F_ + f];
    coef[5][h] = ab[(H_ + h) * F_ + f];
  }
  for (int i = tid; i < TW * PITCH; i += 256) { xs_hi[i] = 0; xs_lo[i] = 0; }

  const float* b0r = X0 + (size_t)((b * 2 + 0) * H_) * FT + f * T_;
  const float* b0i = X0 + (size_t)((b * 2 + 1) * H_) * FT + f * T_;
  const float* b1r = X1 + (size_t)((b * 2 + 0) * H_) * FT + f * T_;
  const float* b1i = X1 + (size_t)((b * 2 + 1) * H_) * FT + f * T_;

  float4v acc[MTW][3];
  #pragma unroll
  for (int mt = 0; mt < MTW; ++mt)
    #pragma unroll
    for (int nt = 0; nt < 3; ++nt) acc[mt][nt] = (float4v)(0.f);

  const short8* wp = (const short8*)wpk;
  for (int half = 0; half < 2; ++half) {
    __syncthreads();
    for (int i = tid; i < 32 * TW; i += 256) {
      int hh = i / TW, tl = i % TW;
      int t = t0 + tl;
      if (t >= T_) continue;
      int h = half * 32 + hh;
      float xr = b0r[h * FT + t], xi = b0i[h * FT + t];
      float vr, vi;
      if (PRO == 1) {
        float er, ei;
        cexp_f(xr, xi, er, ei);
        vr = lrelu_f(er * coef[0][h] + ei * coef[1][h] + coef[4][h]);
        vi = lrelu_f(er * coef[2][h] + ei * coef[3][h] + coef[5][h]);
      } else {
        float yr = b1r[h * FT + t], yi = b1i[h * FT + t];
        float mr = xr * yr - xi * yi;
        float mi = xr * yi + xi * yr;
        vr = lrelu_f(mr * coef[0][h] + mi * coef[1][h] + coef[4][h]);
        vi = lrelu_f(mr * coef[2][h] + mi * coef[3][h] + coef[5][h]);
      }
      int cs0 = hh * 2, cs1 = hh * 2 + 1;
      short hr = f2bf(vr), hi2 = f2bf(vi);
      xs_hi[tl * PITCH + cs0] = hr;
      xs_lo[tl * PITCH + cs0] = f2bf(vr - bf2f(hr));
      xs_hi[tl * PITCH + cs1] = hi2;
      xs_lo[tl * PITCH + cs1] = f2bf(vi - bf2f(hi2));
    }
    __syncthreads();
    #pragma unroll
    for (int s2 = 0; s2 < 2; ++s2) {
      int s = half * 2 + s2;
      short8 Bh[3], Bl[3];
      #pragma unroll
      for (int nt = 0; nt < 3; ++nt) {
        int off = (wbase + nt * 16 + n) * PITCH + s2 * 32 + q * 8;
        Bh[nt] = *(const short8*)&xs_hi[off];
        Bl[nt] = *(const short8*)&xs_lo[off];
      }
      #pragma unroll
      for (int mt = 0; mt < MTW; ++mt) {
        int mtg = mh * 4 + mt;
        if (mtg >= MT) continue;
        short8 Ah = wp[((0 * NSTEP + s) * MT + mtg) * 64 + lane];
        short8 Al = wp[((1 * NSTEP + s) * MT + mtg) * 64 + lane];
        #pragma unroll
        for (int nt = 0; nt < 3; ++nt) {
          acc[mt][nt] = __builtin_amdgcn_mfma_f32_16x16x32_bf16(Ah, Bh[nt], acc[mt][nt], 0, 0, 0);
          acc[mt][nt] = __builtin_amdgcn_mfma_f32_16x16x32_bf16(Ah, Bl[nt], acc[mt][nt], 0, 0, 0);
          acc[mt][nt] = __builtin_amdgcn_mfma_f32_16x16x32_bf16(Al, Bh[nt], acc[mt][nt], 0, 0, 0);
        }
      }
    }
  }

  float* Yp = Y + (size_t)b * COUT2 * FT + f * T_;
  #pragma unroll
  for (int nt = 0; nt < 3; ++nt) {
    int t = t0 + wbase + nt * 16 + n;
    if (t >= T_) continue;
    #pragma unroll
    for (int mt = 0; mt < MTW; ++mt) {
      int mtg = mh * 4 + mt;
      if (mtg >= MT) continue;
      #pragma unroll
      for (int r = 0; r < 4; ++r) {
        int o2 = mtg * 16 + q * 4 + r;
        if (o2 >= COUT2) continue;
        int po = o2 / COUT, ho = o2 % COUT;
        float br = bias[ho], bi = bias[COUT + ho];
        float badd = (po == 0) ? br - bi : br + bi;
        Yp[o2 * FT + t] = acc[mt][nt][r] + badd;
      }
    }
  }
}

// ======== MFMA complex conv, CIN2=16, K=8 (real-ified), T-split ========
__global__ __launch_bounds__(256) void k_cconv16(
    const float* __restrict__ X, const short* __restrict__ wpk,
    const float* __restrict__ bias, float* __restrict__ Y) {
  constexpr int MT = 8, NSTEP = 4, PITCH = 24, ROWS = TW + 7, COUT = 64, COUT2 = 128;
  __shared__ short xs_hi[ROWS * PITCH];
  __shared__ short xs_lo[ROWS * PITCH];
  int f = blockIdx.x;
  int b = blockIdx.y;
  int t0 = blockIdx.z * TW;
  int tid = threadIdx.x;

  for (int i = tid; i < ROWS * PITCH; i += 256) { xs_hi[i] = 0; xs_lo[i] = 0; }
  __syncthreads();

  const float* Xp = X + (size_t)b * 16 * FT + f * T_;
  for (int i = tid; i < 16 * ROWS; i += 256) {
    int c = i / ROWS, rr = i % ROWS;
    int t = t0 + rr - 7;
    if (t < 0 || t >= T_) continue;
    float v = Xp[c * FT + t];
    short hi = f2bf(v);
    short lo = f2bf(v - bf2f(hi));
    xs_hi[rr * PITCH + c] = hi;
    xs_lo[rr * PITCH + c] = lo;
  }
  __syncthreads();

  int lane = tid & 63;
  int wv = __builtin_amdgcn_readfirstlane(tid >> 6);
  int mh = wv >> 1;
  int tc = wv & 1;
  int q = lane >> 4;
  int n = lane & 15;
  int wbase = tc * 48;

  float4v acc[4][3];
  #pragma unroll
  for (int mt = 0; mt < 4; ++mt)
    #pragma unroll
    for (int nt = 0; nt < 3; ++nt) acc[mt][nt] = (float4v)(0.f);

  const short8* wp = (const short8*)wpk;
  #pragma unroll
  for (int s = 0; s < NSTEP; ++s) {
    int tap = s * 2 + (q >> 1);
    int coff = (q & 1) * 8;
    short8 Bh[3], Bl[3];
    #pragma unroll
    for (int nt = 0; nt < 3; ++nt) {
      int off = (wbase + nt * 16 + n + tap) * PITCH + coff;
      Bh[nt] = *(const short8*)&xs_hi[off];
      Bl[nt] = *(const short8*)&xs_lo[off];
    }
    #pragma unroll
    for (int mt = 0; mt < 4; ++mt) {
      int mtg = mh * 4 + mt;
      short8 Ah = wp[((0 * NSTEP + s) * MT + mtg) * 64 + lane];
      short8 Al = wp[((1 * NSTEP + s) * MT + mtg) * 64 + lane];
      #pragma unroll
      for (int nt = 0; nt < 3; ++nt) {
        acc[mt][nt] = __builtin_amdgcn_mfma_f32_16x16x32_bf16(Ah, Bh[nt], acc[mt][nt], 0, 0, 0);
        acc[mt][nt] = __builtin_amdgcn_mfma_f32_16x16x32_bf16(Ah, Bl[nt], acc[mt][nt], 0, 0, 0);
        acc[mt][nt] = __builtin_amdgcn_mfma_f32_16x16x32_bf16(Al, Bh[nt], acc[mt][nt], 0, 0, 0);
      }
    }
  }

  float* Yp = Y + (size_t)b * COUT2 * FT + f * T_;
  #pragma unroll
  for (int nt = 0; nt < 3; ++nt) {
    int t = t0 + wbase + nt * 16 + n;
    if (t >= T_) continue;
    #pragma unroll
    for (int mt = 0; mt < 4; ++mt) {
      #pragma unroll
      for (int r = 0; r < 4; ++r) {
        int o2 = (mh * 4 + mt) * 16 + q * 4 + r;
        int po = o2 / COUT, ho = o2 % COUT;
        float br = bias[ho], bi = bias[COUT + ho];
        float badd = (po == 0) ? br - bi : br + bi;
        Yp[o2 * FT + t] = acc[mt][nt][r] + badd;
      }
    }
  }
}

// ---------------- cExp (out-of-place; output also feeds k_fuse) -----------
__global__ void k_cexp(const float* __restrict__ X, float* __restrict__ Y) {
  int i = blockIdx.x * blockDim.x + threadIdx.x;
  if (i >= B_ * H_ * FT) return;
  int b = i / (H_ * FT);
  int r = i % (H_ * FT);
  int i0 = (b * 2) * H_ * FT + r;
  int i1 = i0 + H_ * FT;
  float er, ei;
  cexp_f(X[i0], X[i1], er, ei);
  Y[i0] = er;
  Y[i1] = ei;
}

__global__ void k_td1(const float* __restrict__ ts, const float* __restrict__ t8,
                      float* __restrict__ td1) {
  int i = blockIdx.x * blockDim.x + threadIdx.x;
  if (i >= B_ * 2 * FT) return;
  int bp = i / FT; int r = i % FT;
  const float* a = ts + bp * C_IN * FT + r;
  const float* c2 = t8 + bp * C_IN * FT + r;
  float acc = 0.f;
  #pragma unroll
  for (int c = 0; c < C_IN; ++c) acc += a[c * FT] - c2[c * FT];
  td1[i] = acc * (1.f / C_IN);
}

// ------------- fuse: cconv(concat) -> tgate -> blend -------------
__global__ void k_fuse(const float* __restrict__ tl1, const float* __restrict__ tl2,
                       const float* __restrict__ td1, const float* __restrict__ td2,
                       const float* __restrict__ cw, const float* __restrict__ cwb,
                       const float* __restrict__ fgt, const float* __restrict__ fgb,
                       float* __restrict__ td) {
  int i = blockIdx.x * blockDim.x + threadIdx.x;
  if (i >= B_ * FT) return;
  int b = i / FT; int r = i % FT; int f = r / T_;
  const float* x1r = tl1 + (b * 2) * H_ * FT + r;
  const float* x1i = x1r + H_ * FT;
  const float* x2r = tl2 + (b * 2) * H_ * FT + r;
  const float* x2i = x2r + H_ * FT;
  float fr = 0.f, fi = 0.f;
  for (int c = 0; c < H_; ++c) {
    float w1r = cw[c], w2r = cw[H_ + c], w1i = cw[2 * H_ + c], w2i = cw[3 * H_ + c];
    float a1r = x1r[c * FT], a1i = x1i[c * FT];
    float a2r = x2r[c * FT], a2i = x2i[c * FT];
    fr += w1r * a1r - w1i * a1i + w2r * a2r - w2i * a2i;
    fi += w1r * a1i + w1i * a1r + w2r * a2i + w2i * a2r;
  }
  fr += cwb[0] - cwb[1];
  fi += cwb[0] + cwb[1];
  float t00 = fgt[f], t01 = fgt[F_ + f], t10 = fgt[2 * F_ + f], t11 = fgt[3 * F_ + f];
  float gr = sigmoid_f(fr * t00 + fi * t01 + fgb[f]);
  float gi = sigmoid_f(fr * t10 + fi * t11 + fgb[F_ + f]);
  float gg = gr * gi + (1.f - gr) * (1.f - gi);
  int i0 = (b * 2) * FT + r, i1 = i0 + FT;
  td[i0] = td1[i0] * gg + td2[i0] * (1.f - gg);
  td[i1] = td1[i1] * gg + td2[i1] * (1.f - gg);
}

// ------------- iSTFT frames: folded rotation inverse DFT -------------
__global__ __launch_bounds__(320) void k_iframes(const float* __restrict__ sp,
                                                 float* __restrict__ frames) {
  __shared__ float Xr[F_], Xi[F_];
  int blk = blockIdx.x;
  int t = blk % T_;
  int b = blk / T_;
  int tid = threadIdx.x;
  for (int i = tid; i < F_; i += 320) {
    Xr[i] = sp[(b * 2 + 0) * FT + i * T_ + t];
    Xi[i] = sp[(b * 2 + 1) * FT + i * T_ + t];
  }
  __syncthreads();
  int n = tid;
  if (n <= 256) {
    float sd, cd;
    sincosf((PI2 / NFFT) * n, &sd, &cd);
    float cs = cd, sn = sd;
    float ac = 0.f, as = 0.f;
    for (int f = 1; f < 256; ++f) {
      ac += Xr[f] * cs;
      as += Xi[f] * sn;
      float t2 = cs * cd - sn * sd;
      sn = sn * cd + cs * sd;
      cs = t2;
    }
    float base = Xr[0] + Xr[256] * (1.f - 2.f * (n & 1));
    float win = 0.5f - 0.5f * cd;
    float scale = win * (1.f / NFFT);
    float* fr = frames + (size_t)(b * T_ + t) * NFFT;
    fr[n] = (base + 2.f * ac - 2.f * as) * scale;
    if (n >= 1 && n <= 255)
      fr[NFFT - n] = (base + 2.f * ac + 2.f * as) * scale;
  }
}

// ------------- overlap-add + wsum normalize + center-crop -------------
__global__ void k_ola(const float* __restrict__ frames, float* __restrict__ out) {
  int i = blockIdx.x * blockDim.x + threadIdx.x;
  if (i >= B_ * LEN) return;
  int b = i / LEN; int j = i % LEN;
  int p = j + PADL;
  int t0 = p / HOP; int n0 = p - t0 * HOP;
  float acc = 0.f, wsum = 0.f;
  if (t0 < T_) {
    acc += frames[(b * T_ + t0) * NFFT + n0];
    float w = 0.5f - 0.5f * cosf((PI2 / NFFT) * n0);
    wsum += w * w;
  }
  int t1 = t0 - 1, n1 = n0 + HOP;
  if (t1 >= 0 && t1 < T_) {
    acc += frames[(b * T_ + t1) * NFFT + n1];
    float w = 0.5f - 0.5f * cosf((PI2 / NFFT) * n1);
    wsum += w * w;
  }
  out[i] = acc / fmaxf(wsum, 1e-11f);
}

extern "C" void kernel_launch(void* const* d_in, const int* in_sizes, int n_in,
                              void* d_out, int out_size, void* d_ws, size_t ws_size,
                              hipStream_t stream) {
  const float* mix   = (const float*)d_in[0];
  const float* fs_w  = (const float*)d_in[1];
  const float* fs_b  = (const float*)d_in[2];
  const float* fr_w  = (const float*)d_in[3];
  const float* fr_b  = (const float*)d_in[4];
  const float* c1r_w = (const float*)d_in[5];
  const float* c1r_b = (const float*)d_in[6];
  const float* c1i_w = (const float*)d_in[7];
  const float* c1i_b = (const float*)d_in[8];
  const float* c1_w  = (const float*)d_in[9];
  const float* c1_b  = (const float*)d_in[10];
  const float* c2r_w = (const float*)d_in[11];
  const float* c2r_b = (const float*)d_in[12];
  const float* c2i_w = (const float*)d_in[13];
  const float* c2i_b = (const float*)d_in[14];
  const float* c2_w  = (const float*)d_in[15];
  const float* c2_b  = (const float*)d_in[16];
  const float* a1_t  = (const float*)d_in[17];
  const float* a1_b  = (const float*)d_in[18];
  const float* a2_t  = (const float*)d_in[19];
  const float* a2_b  = (const float*)d_in[20];
  const float* c3r_w = (const float*)d_in[21];
  const float* c3r_b = (const float*)d_in[22];
  const float* c3i_w = (const float*)d_in[23];
  const float* c3i_b = (const float*)d_in[24];
  const float* c3_w  = (const float*)d_in[25];
  const float* c3_b  = (const float*)d_in[26];
  const float* c4r_w = (const float*)d_in[27];
  const float* c4r_b = (const float*)d_in[28];
  const float* c4i_w = (const float*)d_in[29];
  const float* c4i_b = (const float*)d_in[30];
  const float* c4_w  = (const float*)d_in[31];
  const float* c4_b  = (const float*)d_in[32];
  const float* a3_t  = (const float*)d_in[33];
  const float* a3_b  = (const float*)d_in[34];
  const float* a4_t  = (const float*)d_in[35];
  const float* a4_b  = (const float*)d_in[36];
  const float* f1_w  = (const float*)d_in[37];
  const float* f1_b  = (const float*)d_in[38];
  const float* f2_w  = (const float*)d_in[39];
  const float* f2_b  = (const float*)d_in[40];
  const float* cw_w  = (const float*)d_in[41];
  const float* cw_b  = (const float*)d_in[42];
  const float* fg_t  = (const float*)d_in[43];
  const float* fg_b  = (const float*)d_in[44];

  const size_t S8 = (size_t)B_ * 2 * C_IN * FT;
  const size_t SH = (size_t)B_ * 2 * H_ * FT;
  const size_t S1 = (size_t)B_ * 2 * FT;
  float* ws  = (float*)d_ws;
  float* ts0 = ws;
  float* ts  = ts0 + S8;
  float* A   = ts + S8;
  float* Bb  = A + SH;
  float* Cc  = Bb + SH;
  float* td1 = Cc + SH;
  float* td2 = td1 + S1;
  float* tdf = td2 + S1;
  float* tdr = tdf + S1;
  float* s8  = ts0;
  float* frames = ts0;

  short* wtail = (short*)(tdr + S1);
  constexpr int SZ_C8K1   = 2 * 1  * 4 * 64 * 8;
  constexpr int SZ_C64K1  = 2 * 2  * 4 * 64 * 8;
  constexpr int SZ_C64K8  = 2 * 16 * 4 * 64 * 8;
  constexpr int SZ_CC128  = 2 * 4  * 8 * 64 * 8;
  constexpr int SZ_CF     = 2 * 4  * 1 * 64 * 8;
  short* w_c1r = wtail;
  short* w_c1i = w_c1r + SZ_C8K1;
  short* w_c2r = w_c1i + SZ_C64K1;
  short* w_c2i = w_c2r + SZ_C64K8;
  short* w_c3r = w_c2i + SZ_C64K8;
  short* w_c3i = w_c3r + SZ_C8K1;
  short* w_c4r = w_c3i + SZ_C64K1;
  short* w_c4i = w_c4r + SZ_C64K8;
  short* w_cc1 = w_c4i + SZ_C64K8;
  short* w_cc2 = w_cc1 + SZ_CC128;
  short* w_cc3 = w_cc2 + SZ_CC128;
  short* w_cc4 = w_cc3 + SZ_CC128;
  short* w_cf1 = w_cc4 + SZ_CC128;
  short* w_cf2 = w_cf1 + SZ_CF;

  const int nH = B_ * H_ * FT;
  const int nP = B_ * FT;
  const dim3 rgrid(F_, B_ * 2, 2);   // real convs: (f, b*2+p, t-half)
  const dim3 cgrid(F_, B_, 2);       // complex convs: (f, b, t-half)

  k_repack_all<<<dim3(256, 14), 256, 0, stream>>>(
      c1r_w, c1i_w, c2r_w, c2i_w, c3r_w, c3i_w, c4r_w, c4i_w,
      c1_w, c2_w, c3_w, c4_w, f1_w, f2_w,
      w_c1r, w_c1i, w_c2r, w_c2i, w_c3r, w_c3i, w_c4r, w_c4i,
      w_cc1, w_cc2, w_cc3, w_cc4, w_cf1, w_cf2);

  // STFT + frequency mixing
  k_stft<<<B_ * C_IN * T_, 320, 0, stream>>>(mix, ts0);
  k_fmix<C_IN><<<dim3(F_, B_ * C_IN), 192, 0, stream>>>(ts0, fs_w, fs_b, ts);

  // ---- branch 1 ----
  k_conv_mfma<C_IN, 1, 2><<<rgrid, 256, 0, stream>>>(ts, w_c1r, c1r_b, A);     // cLog+c1r
  k_conv_mfma<H_, 1, 1><<<rgrid, 256, 0, stream>>>(A, w_c1i, c1i_b, Bb);       // lrelu+c1i
  k_cconv128<128, 1><<<cgrid, 256, 0, stream>>>(Bb, Bb, w_cc1, a1_t, a1_b, c1_b, A); // cexp+trelu+c1
  k_conv_mfma<H_, 8, 2><<<rgrid, 256, 0, stream>>>(A, w_c2r, c2r_b, Bb);       // cLog+c2r
  k_conv_mfma<H_, 8, 1><<<rgrid, 256, 0, stream>>>(Bb, w_c2i, c2i_b, A);       // lrelu+c2i
  k_cexp<<<(nH + 255) / 256, 256, 0, stream>>>(A, Bb);                          // Bb = tl1
  k_cconv16<<<cgrid, 256, 0, stream>>>(ts, w_cc2, c2_b, A);                     // tc
  k_cconv128<16, 2><<<cgrid, 256, 0, stream>>>(Bb, A, w_cf1, a2_t, a2_b, f1_b, s8); // cmul+trelu+f1
  k_td1<<<(B_ * 2 * FT + 255) / 256, 256, 0, stream>>>(ts, s8, td1);

  // ---- branch 2 ----
  k_conv_mfma<C_IN, 1, 2><<<rgrid, 256, 0, stream>>>(ts, w_c3r, c3r_b, A);
  k_conv_mfma<H_, 1, 1><<<rgrid, 256, 0, stream>>>(A, w_c3i, c3i_b, Cc);
  k_cconv128<128, 1><<<cgrid, 256, 0, stream>>>(Cc, Cc, w_cc3, a3_t, a3_b, c3_b, A);
  k_conv_mfma<H_, 8, 2><<<rgrid, 256, 0, stream>>>(A, w_c4r, c4r_b, Cc);
  k_conv_mfma<H_, 8, 1><<<rgrid, 256, 0, stream>>>(Cc, w_c4i, c4i_b, A);
  k_cexp<<<(nH + 255) / 256, 256, 0, stream>>>(A, Cc);                          // Cc = tl2
  k_cconv16<<<cgrid, 256, 0, stream>>>(ts, w_cc4, c4_b, A);
  k_cconv128<2, 2><<<cgrid, 256, 0, stream>>>(Cc, A, w_cf2, a4_t, a4_b, f2_b, td2);

  // ---- fuse + unmix + iSTFT ----
  k_fuse<<<(nP + 255) / 256, 256, 0, stream>>>(Bb, Cc, td1, td2, cw_w, cw_b, fg_t, fg_b, tdf);
  k_fmix<1><<<dim3(F_, B_), 192, 0, stream>>>(tdf, fr_w, fr_b, tdr);
  k_iframes<<<B_ * T_, 320, 0, stream>>>(tdr, frames);
  k_ola<<<(B_ * LEN + 255) / 256, 256, 0, stream>>>(frames, (float*)d_out);
}